// Round 1
// baseline (67.934 us; speedup 1.0000x reference)
//
#include <hip/hip_runtime.h>
#include <math.h>

#define BB 64
#define PP 16
#define FIN 672
#define HH 2048
#define AA 32
#define MM (BB*PP)     // 1024
#define EPSBN 1e-5f

// ---------------------------------------------------------------------------
// Kernel 1: fused BN0 + GEMM1 (fp32, M=1024 x K=672 x N=2048) + BN1 + LIF.
// Produces S[b*16+p][n] = sum_k c_k * spike_k  (weighted spike count).
// Tiling: 64x64 block tile, BK=16, 256 threads, 4x4 micro-tile per thread.
// ---------------------------------------------------------------------------
__global__ __launch_bounds__(256) void k_gemm1_lif(
    const float* __restrict__ x, const float* __restrict__ w1,
    const float* __restrict__ bias1,
    const float* __restrict__ g0, const float* __restrict__ b0,
    const float* __restrict__ m0, const float* __restrict__ v0,
    const float* __restrict__ g1, const float* __restrict__ b1,
    const float* __restrict__ m1, const float* __restrict__ v1,
    float* __restrict__ S)
{
    __shared__ float As[16][68];   // [k][m], pad 68 -> 16B-aligned rows, no 4-way banks
    __shared__ float Bs[16][68];   // [k][n]

    const int tid = threadIdx.x;
    const int bx  = blockIdx.x;    // N tiles: 0..31
    const int by  = blockIdx.y;    // M tiles: 0..15

    // A (x) loading role: 64 rows x 16 k, one float4 per thread, BN0 fused.
    const int ar   = tid >> 2;            // 0..63
    const int ac   = (tid & 3) << 2;      // 0,4,8,12
    const int grow = by * 64 + ar;
    const int pA   = grow & 15;
    const float a0  = g0[pA] / sqrtf(v0[pA] + EPSBN);
    const float be0 = b0[pA] - m0[pA] * a0;
    const float* xrow = x + (size_t)grow * FIN;

    // B (w1) loading role: 16 k x 64 cols, one float4 per thread.
    const int brk = tid >> 4;             // 0..15
    const int bcc = (tid & 15) << 2;      // 0..60

    const int tx = tid & 15;
    const int ty = tid >> 4;

    float acc[4][4];
    #pragma unroll
    for (int i = 0; i < 4; ++i)
        #pragma unroll
        for (int j = 0; j < 4; ++j) acc[i][j] = 0.f;

    for (int kt = 0; kt < FIN; kt += 16) {
        float4 av = *(const float4*)(xrow + kt + ac);
        float4 bv = *(const float4*)(w1 + (size_t)(kt + brk) * HH + bx * 64 + bcc);
        As[ac + 0][ar] = fmaf(a0, av.x, be0);
        As[ac + 1][ar] = fmaf(a0, av.y, be0);
        As[ac + 2][ar] = fmaf(a0, av.z, be0);
        As[ac + 3][ar] = fmaf(a0, av.w, be0);
        *(float4*)&Bs[brk][bcc] = bv;
        __syncthreads();
        #pragma unroll
        for (int k = 0; k < 16; ++k) {
            float4 a4 = *(const float4*)&As[k][ty << 2];
            float4 b4 = *(const float4*)&Bs[k][tx << 2];
            float aa[4] = {a4.x, a4.y, a4.z, a4.w};
            float bb[4] = {b4.x, b4.y, b4.z, b4.w};
            #pragma unroll
            for (int i = 0; i < 4; ++i)
                #pragma unroll
                for (int j = 0; j < 4; ++j)
                    acc[i][j] = fmaf(aa[i], bb[j], acc[i][j]);
        }
        __syncthreads();
    }

    // Weighted-spike coefficients c_t = (1 - 2^-(16-t))/16 (exact dyadic).
    const float KC[16] = {
        (1.0f-0x1p-16f)*0.0625f,(1.0f-0x1p-15f)*0.0625f,(1.0f-0x1p-14f)*0.0625f,(1.0f-0x1p-13f)*0.0625f,
        (1.0f-0x1p-12f)*0.0625f,(1.0f-0x1p-11f)*0.0625f,(1.0f-0x1p-10f)*0.0625f,(1.0f-0x1p-9f)*0.0625f,
        (1.0f-0x1p-8f)*0.0625f,(1.0f-0x1p-7f)*0.0625f,(1.0f-0x1p-6f)*0.0625f,(1.0f-0x1p-5f)*0.0625f,
        (1.0f-0x1p-4f)*0.0625f,(1.0f-0x1p-3f)*0.0625f,(1.0f-0x1p-2f)*0.0625f,(1.0f-0x1p-1f)*0.0625f
    };

    const int col0 = bx * 64 + (tx << 2);
    float4 bias4 = *(const float4*)(bias1 + col0);
    const float bias_arr[4] = {bias4.x, bias4.y, bias4.z, bias4.w};

    #pragma unroll
    for (int i = 0; i < 4; ++i) {
        const int r = by * 64 + (ty << 2) + i;
        const int p = r & 15;
        const float a1  = g1[p] / sqrtf(v1[p] + EPSBN);
        const float be1 = b1[p] - m1[p] * a1;
        float out4[4];
        #pragma unroll
        for (int j = 0; j < 4; ++j) {
            // h after BN1
            const float h = fmaf(a1, acc[i][j] + bias_arr[j], be1);
            // LIF, 16 steps, hard reset; match reference op order v += (h-v)/2
            float v = 0.f, s = 0.f;
            #pragma unroll
            for (int t = 0; t < 16; ++t) {
                v = v + (h - v) * 0.5f;
                if (v >= 1.0f) { s += KC[t]; v = 0.f; }
            }
            out4[j] = s;
        }
        float4 sv; sv.x = out4[0]; sv.y = out4[1]; sv.z = out4[2]; sv.w = out4[3];
        *(float4*)(S + (size_t)r * HH + col0) = sv;
    }
}

// ---------------------------------------------------------------------------
// Kernel 2a: partial GEMM2: part[kc][row][col] = sum_{k in chunk} S[row,k]*w2[k,col]
// Grid: (128 row-groups of 8) x (8 K-chunks of 256). w2 chunk staged in LDS.
// ---------------------------------------------------------------------------
__global__ __launch_bounds__(256) void k_gemm2_part(
    const float* __restrict__ S, const float* __restrict__ w2,
    float* __restrict__ part)
{
    __shared__ float w2s[8192];   // 256 k x 32 cols = 32 KB
    const int tid = threadIdx.x;
    const int rg  = blockIdx.x;   // 0..127
    const int kc  = blockIdx.y;   // 0..7

    const float4* src = (const float4*)(w2 + (size_t)kc * 8192);
    #pragma unroll
    for (int i = tid; i < 2048; i += 256) ((float4*)w2s)[i] = src[i];
    __syncthreads();

    const int rw  = tid >> 5;     // 0..7
    const int col = tid & 31;
    const int row = rg * 8 + rw;
    const float* Sp = S + (size_t)row * HH + kc * 256;

    float acc0 = 0.f, acc1 = 0.f;
    #pragma unroll 4
    for (int j = 0; j < 256; j += 4) {
        float4 s4 = *(const float4*)(Sp + j);
        acc0 = fmaf(s4.x, w2s[(j + 0) * 32 + col], acc0);
        acc1 = fmaf(s4.y, w2s[(j + 1) * 32 + col], acc1);
        acc0 = fmaf(s4.z, w2s[(j + 2) * 32 + col], acc0);
        acc1 = fmaf(s4.w, w2s[(j + 3) * 32 + col], acc1);
    }
    part[((size_t)kc * MM + row) * AA + col] = acc0 + acc1;
}

// ---------------------------------------------------------------------------
// Kernel 2b: reduce 8 partials + folded BN2 / bias2 / ns-LIF-mean + tanh*2.
// ---------------------------------------------------------------------------
__global__ __launch_bounds__(256) void k_finish(
    const float* __restrict__ part, const float* __restrict__ bias2,
    const float* __restrict__ g2, const float* __restrict__ b2,
    const float* __restrict__ m2, const float* __restrict__ v2,
    float* __restrict__ out)
{
    const int i   = blockIdx.x * 256 + threadIdx.x;  // 0..32767
    const int col = i & 31;
    const int row = i >> 5;
    const int p   = row & 15;
    float acc = 0.f;
    #pragma unroll
    for (int s = 0; s < 8; ++s) acc += part[(size_t)s * MM * AA + i];
    const float a2   = g2[p] / sqrtf(v2[p] + EPSBN);
    const float be2  = b2[p] - m2[p] * a2;
    const float Csum = 0.9375f + 0x1p-20f;  // sum_k c_k = 1 - (1-2^-16)/16
    const float val  = fmaf(a2, acc + Csum * bias2[col], Csum * be2);
    out[i] = 2.0f * tanhf(val);
}

extern "C" void kernel_launch(void* const* d_in, const int* in_sizes, int n_in,
                              void* d_out, int out_size, void* d_ws, size_t ws_size,
                              hipStream_t stream) {
    (void)in_sizes; (void)n_in; (void)out_size; (void)ws_size;
    const float* x     = (const float*)d_in[0];
    const float* w1    = (const float*)d_in[1];
    const float* bias1 = (const float*)d_in[2];
    const float* w2    = (const float*)d_in[3];
    const float* bias2 = (const float*)d_in[4];
    const float* g0 = (const float*)d_in[5];
    const float* b0 = (const float*)d_in[6];
    const float* m0 = (const float*)d_in[7];
    const float* v0 = (const float*)d_in[8];
    const float* g1 = (const float*)d_in[9];
    const float* b1 = (const float*)d_in[10];
    const float* m1 = (const float*)d_in[11];
    const float* v1 = (const float*)d_in[12];
    const float* g2 = (const float*)d_in[13];
    const float* b2 = (const float*)d_in[14];
    const float* m2 = (const float*)d_in[15];
    const float* v2 = (const float*)d_in[16];

    float* S    = (float*)d_ws;                                          // 1024*2048*4 = 8 MB
    float* part = (float*)((char*)d_ws + (size_t)MM * HH * sizeof(float)); // + 1 MB
    float* out  = (float*)d_out;

    k_gemm1_lif<<<dim3(32, 16), 256, 0, stream>>>(x, w1, bias1,
                                                  g0, b0, m0, v0,
                                                  g1, b1, m1, v1, S);
    k_gemm2_part<<<dim3(128, 8), 256, 0, stream>>>(S, w2, part);
    k_finish<<<dim3(128), 256, 0, stream>>>(part, bias2, g2, b2, m2, v2, out);
}